// Round 6
// baseline (131.342 us; speedup 1.0000x reference)
//
#include <hip/hip_runtime.h>
#include <hip/hip_bf16.h>

#define DIM   1024
#define SEQL  4096
#define NTOK  16384
#define NATT  90
#define NATTP 96

typedef __attribute__((ext_vector_type(8))) short frag_ab;   // 8 x bf16
typedef __attribute__((ext_vector_type(4))) float frag_cd;   // 4 x f32

typedef unsigned int u32;
typedef const __attribute__((address_space(1))) u32* gp_t;
typedef __attribute__((address_space(3))) u32* lp_t;

static __device__ __forceinline__ unsigned short f2bf(float f) {
    unsigned int u = __float_as_uint(f);
    return (unsigned short)((u + 0x7fffu + ((u >> 16) & 1u)) >> 16);  // RNE
}
static __device__ __forceinline__ ushort4 f4tobf(float4 v) {
    ushort4 r; r.x = f2bf(v.x); r.y = f2bf(v.y); r.z = f2bf(v.z); r.w = f2bf(v.w);
    return r;
}

// ---------- merged cvt: w2 -> bf16 (96 rows, zero-padded) + wo -> bf16 ----------
__global__ __launch_bounds__(256) void cvt_kernel(
    const float* __restrict__ w2, const float* __restrict__ wo,
    unsigned short* __restrict__ w2b, unsigned short* __restrict__ wob)
{
    const int bid = blockIdx.x;
    if (bid < 96) {
        const int i = bid * 256 + threadIdx.x;      // f4 idx, 96*256
        const int row = i >> 8;
        float4 v = make_float4(0.f, 0.f, 0.f, 0.f);
        if (row < NATT) v = ((const float4*)w2)[i];
        *(ushort4*)(w2b + (size_t)i * 4) = f4tobf(v);
    } else {
        const int i = (bid - 96) * 256 + threadIdx.x;
        float4 v = ((const float4*)wo)[i];
        *(ushort4*)(wob + (size_t)i * 4) = f4tobf(v);
    }
}

// ---------- stage 1: att = x @ w2b^T + b2 -> coeff[9]+absum ----------
// 16 tokens/block, x staged coalesced into swizzled LDS, K-split 4 waves,
// LDS-atomic reduction. LDS ~39 KB -> 4 blocks/CU.
#define ATOK 16

__global__ __launch_bounds__(256) void att_coeff_kernel(
    const float* __restrict__ x, const unsigned short* __restrict__ w2b,
    const float* __restrict__ b2, float* __restrict__ cws)
{
    __shared__ unsigned short xs[ATOK * 1024];   // chunk-swizzled bf16, 32 KB
    __shared__ float summ[ATOK * NATTP];         // 6 KB

    const int tid  = threadIdx.x;
    const int wave = tid >> 6, lane = tid & 63;
    const int fr = lane & 15, kq = lane >> 4;
    const int tok0 = blockIdx.x * ATOK;

    // init summ with bias (cols >= 90 zero)
    for (int o = tid; o < ATOK * NATTP; o += 256) {
        const int m = o % NATTP;
        summ[o] = (m < NATT) ? b2[m] : 0.f;
    }

    // stage x: each wave loads full rows (coalesced 1KB/inst), swizzled bf16 store
    // chunk c (16B) of row r stored at LDS chunk (c ^ (r&7))
    #pragma unroll
    for (int t = 0; t < 4; ++t) {
        const int row = t * 4 + wave;
        const float4* xr = (const float4*)(x + (size_t)(tok0 + row) * DIM);
        #pragma unroll
        for (int tt = 0; tt < 4; ++tt) {
            const int c4 = tt * 64 + lane;            // float4 index 0..255
            float4 v = xr[c4];
            const int ch = c4 >> 1, half = c4 & 1;
            *(ushort4*)(&xs[row * 1024 + ((ch ^ (row & 7)) * 8 + half * 4)]) = f4tobf(v);
        }
    }
    __syncthreads();

    // MFMA: wave w owns K chunk-range [w*32, w*32+32)
    frag_cd acc[6] = {};
    const unsigned short* wrow = w2b + (size_t)fr * DIM + wave * 256 + kq * 8;

    #pragma unroll
    for (int kk = 0; kk < 8; ++kk) {
        const int ch = wave * 32 + kk * 4 + kq;
        frag_ab a = *(const frag_ab*)(&xs[fr * 1024 + ((ch ^ (fr & 7)) * 8)]);
        #pragma unroll
        for (int f = 0; f < 6; ++f) {
            frag_ab b = *(const frag_ab*)(wrow + (size_t)f * 16 * DIM + kk * 32);
            acc[f] = __builtin_amdgcn_mfma_f32_16x16x32_bf16(a, b, acc[f], 0, 0, 0);
        }
    }

    // reduce K-slices: LDS atomics.  D layout: col = lane&15, row = (lane>>4)*4+r
    const int col = lane & 15, rb = (lane >> 4) * 4;
    #pragma unroll
    for (int f = 0; f < 6; ++f)
        #pragma unroll
        for (int r = 0; r < 4; ++r)
            atomicAdd(&summ[(rb + r) * NATTP + f * 16 + col], acc[f][r]);
    __syncthreads();

    // coeff[k] = sum_j sin(att[9k+j]);  absum = sum att[81..89]
    if (tid < 160) {
        const int t = tid / 10, j = tid - (tid / 10) * 10;
        float s = 0.f;
        if (j < 9) {
            #pragma unroll
            for (int jj = 0; jj < 9; ++jj) s += sinf(summ[t * NATTP + j * 9 + jj]);
        } else {
            #pragma unroll
            for (int m = NATT - 9; m < NATT; ++m) s += summ[t * NATTP + m];
        }
        cws[(size_t)(tok0 + t) * 10 + j] = s;
    }
}

// ---------- stage 2: y stencil, rolling register window ----------
#define TT 32

__global__ __launch_bounds__(256) void y_kernel(
    const float* __restrict__ x, const float* __restrict__ cws,
    unsigned short* __restrict__ ybf)
{
    __shared__ float c[TT][10];
    const int tid  = threadIdx.x;
    const int tok0 = blockIdx.x * TT;

    for (int i = tid; i < TT * 10; i += 256)
        c[i / 10][i % 10] = cws[(size_t)tok0 * 10 + i];
    __syncthreads();

    const int b  = tok0 >> 12;
    const int l0 = tok0 & 4095;
    const float4* xv = (const float4*)x + (size_t)b * SEQL * (DIM / 4) + tid;
    const float4 z4 = make_float4(0.f, 0.f, 0.f, 0.f);

    float4 w[9];
    #pragma unroll
    for (int k = 0; k < 8; ++k) {
        const int src = l0 + k - 4;
        w[k] = (src >= 0 && src < SEQL) ? xv[(size_t)src * (DIM / 4)] : z4;
    }

    ushort4* yp = (ushort4*)(ybf + (size_t)tok0 * DIM + tid * 4);

    #pragma unroll
    for (int t = 0; t < TT; ++t) {
        const int src = l0 + t + 4;
        w[8] = (src < SEQL) ? xv[(size_t)src * (DIM / 4)] : z4;

        float4 acc;
        acc.x = acc.y = acc.z = acc.w = c[t][9];
        #pragma unroll
        for (int k = 0; k < 9; ++k) {
            const float ck = c[t][k];
            acc.x += ck * w[k].x; acc.y += ck * w[k].y;
            acc.z += ck * w[k].z; acc.w += ck * w[k].w;
        }
        yp[(size_t)t * (DIM / 4)] = f4tobf(acc);

        #pragma unroll
        for (int k = 0; k < 8; ++k) w[k] = w[k + 1];
    }
}

// ---------- stage 3: out = y @ wo^T + bo  (256x256, 8-phase counted-vmcnt) ----------
// LDS layout: [dbuf][K-half s][256 rows][4 chunks of 16B], slot-swizzled:
//   slot(row,kq) = row*4 + (kq ^ ((row>>1)&3))  -> 2-way bank access (free)
// Stage unit = (tile, s): A+B, 4 gload_lds/wave. Issue (t+1,s1)@q0, (t+2,s0)@q2.
// Steady state vmcnt(8) at q1/q3 ends: 2-3 units in flight, never drained.

#define VMC8 asm volatile("s_waitcnt vmcnt(8)" ::: "memory")
#define VMC4 asm volatile("s_waitcnt vmcnt(4)" ::: "memory")
#define VMC0 asm volatile("s_waitcnt vmcnt(0)" ::: "memory")
#define BAR  __builtin_amdgcn_s_barrier()

#define STAGE_U(b_, s_, kt_) {                                                        \
    const int slot0 = (wave * 2) * 64 + lane;                                         \
    const int slot1 = slot0 + 64;                                                     \
    const int r0 = slot0 >> 2, c0 = (slot0 & 3) ^ ((r0 >> 1) & 3);                    \
    const int r1 = slot1 >> 2, c1 = (slot1 & 3) ^ ((r1 >> 1) & 3);                    \
    const int hb_ = ((b_) * 2 + (s_)) * 1024;                                         \
    __builtin_amdgcn_global_load_lds((gp_t)(A  + (size_t)(m0 + r0) * DIM + (kt_) * 64 + (s_) * 32 + c0 * 8), \
        (lp_t)(&AsU[(hb_ + (wave * 2) * 64) * 8]), 16, 0, 0);                         \
    __builtin_amdgcn_global_load_lds((gp_t)(A  + (size_t)(m0 + r1) * DIM + (kt_) * 64 + (s_) * 32 + c1 * 8), \
        (lp_t)(&AsU[(hb_ + (wave * 2 + 1) * 64) * 8]), 16, 0, 0);                     \
    __builtin_amdgcn_global_load_lds((gp_t)(Bm + (size_t)(n0 + r0) * DIM + (kt_) * 64 + (s_) * 32 + c0 * 8), \
        (lp_t)(&BsU[(hb_ + (wave * 2) * 64) * 8]), 16, 0, 0);                         \
    __builtin_amdgcn_global_load_lds((gp_t)(Bm + (size_t)(n0 + r1) * DIM + (kt_) * 64 + (s_) * 32 + c1 * 8), \
        (lp_t)(&BsU[(hb_ + (wave * 2 + 1) * 64) * 8]), 16, 0, 0);                     \
  }

#define RD_B(d_, s_, dst) {                                                           \
    const int hb_ = ((d_) * 2 + (s_)) * 1024;                                         \
    { int row = wn + fr;           dst[0] = *(const frag_ab*)(&BsU[(hb_ + row * 4 + (kq ^ ((row >> 1) & 3))) * 8]); } \
    { int row = wn + 16 + fr;      dst[1] = *(const frag_ab*)(&BsU[(hb_ + row * 4 + (kq ^ ((row >> 1) & 3))) * 8]); } \
    { int row = wn + 32 + fr;      dst[2] = *(const frag_ab*)(&BsU[(hb_ + row * 4 + (kq ^ ((row >> 1) & 3))) * 8]); } \
    { int row = wn + 48 + fr;      dst[3] = *(const frag_ab*)(&BsU[(hb_ + row * 4 + (kq ^ ((row >> 1) & 3))) * 8]); } \
  }

#define RD_A(d_, s_, h_, dst) {                                                       \
    const int hb_ = ((d_) * 2 + (s_)) * 1024;                                         \
    { int row = wm + ((h_) * 64)      + fr; dst[0] = *(const frag_ab*)(&AsU[(hb_ + row * 4 + (kq ^ ((row >> 1) & 3))) * 8]); } \
    { int row = wm + ((h_) * 64) + 16 + fr; dst[1] = *(const frag_ab*)(&AsU[(hb_ + row * 4 + (kq ^ ((row >> 1) & 3))) * 8]); } \
    { int row = wm + ((h_) * 64) + 32 + fr; dst[2] = *(const frag_ab*)(&AsU[(hb_ + row * 4 + (kq ^ ((row >> 1) & 3))) * 8]); } \
    { int row = wm + ((h_) * 64) + 48 + fr; dst[3] = *(const frag_ab*)(&AsU[(hb_ + row * 4 + (kq ^ ((row >> 1) & 3))) * 8]); } \
  }

#define MFMA16(base_, av_, bv_)                                                       \
    __builtin_amdgcn_s_setprio(1);                                                    \
    _Pragma("unroll")                                                                 \
    for (int mi_ = 0; mi_ < 4; ++mi_)                                                 \
        _Pragma("unroll")                                                             \
        for (int ni_ = 0; ni_ < 4; ++ni_)                                             \
            acc[(base_) + mi_][ni_] = __builtin_amdgcn_mfma_f32_16x16x32_bf16(        \
                av_[mi_], bv_[ni_], acc[(base_) + mi_][ni_], 0, 0, 0);                \
    __builtin_amdgcn_s_setprio(0);

#define TILE(d_, STG0, STG2, VM1, VM3) {                                              \
    frag_ab b0[4], b1[4], av[4];                                                      \
    RD_B(d_, 0, b0); RD_A(d_, 0, 0, av);                                              \
    STG0;                                                                             \
    BAR;                                                                              \
    MFMA16(0, av, b0);                                                                \
    BAR;                                                                              \
    RD_A(d_, 0, 1, av);                                                               \
    VM1;                                                                              \
    BAR;                                                                              \
    MFMA16(4, av, b0);                                                                \
    BAR;                                                                              \
    RD_B(d_, 1, b1); RD_A(d_, 1, 0, av);                                              \
    STG2;                                                                             \
    BAR;                                                                              \
    MFMA16(0, av, b1);                                                                \
    BAR;                                                                              \
    RD_A(d_, 1, 1, av);                                                               \
    VM3;                                                                              \
    BAR;                                                                              \
    MFMA16(4, av, b1);                                                                \
    BAR;                                                                              \
  }

__global__ __launch_bounds__(512, 2) void gemm_kernel(
    const unsigned short* __restrict__ A,   // y_bf  [16384][1024]
    const unsigned short* __restrict__ Bm,  // wo_bf [1024][1024] (row = out col)
    const float* __restrict__ bo,
    float* __restrict__ out)
{
    __shared__ unsigned short AsU[2 * 2 * 1024 * 8];   // 64 KB
    __shared__ unsigned short BsU[2 * 2 * 1024 * 8];   // 64 KB

    const int tid  = threadIdx.x;
    const int wave = tid >> 6, lane = tid & 63;
    const int fr = lane & 15, kq = lane >> 4;
    const int wm = (wave >> 2) * 128;    // 0 or 128
    const int wn = (wave & 3) * 64;      // 0,64,128,192

    // bijective XCD swizzle: 256 blocks = 8 XCDs x 32
    const int bid = blockIdx.x;
    const int lid = (bid & 7) * 32 + (bid >> 3);
    const int m0  = (lid >> 2) * 256;
    const int n0  = (lid & 3) * 256;

    frag_cd acc[8][4] = {};

    // prologue: (0,s0), (0,s1), (1,s0) -> 12 loads/wave in flight
    STAGE_U(0, 0, 0);
    STAGE_U(0, 1, 0);
    STAGE_U(1, 0, 1);
    VMC8;        // (0,s0) landed
    BAR;

    #pragma unroll 1
    for (int t = 0; t < 14; ++t) {
        const int d = t & 1;
        TILE(d,
             STAGE_U((t + 1) & 1, 1, t + 1),    // (t+1, s1)
             STAGE_U(t & 1, 0, t + 2),          // (t+2, s0)
             VMC8, VMC8);
    }
    // t = 14: stage (15,s1) only
    TILE(0, STAGE_U(1, 1, 15), (void)0, VMC8, VMC4);
    // t = 15: no staging
    TILE(1, (void)0, (void)0, VMC0, (void)0);

    // epilogue
    const int colb = lane & 15, rb = (lane >> 4) * 4;
    #pragma unroll
    for (int ni = 0; ni < 4; ++ni) {
        const int col = n0 + wn + ni * 16 + colb;
        const float bias = bo[col];
        #pragma unroll
        for (int mi = 0; mi < 8; ++mi) {
            #pragma unroll
            for (int r = 0; r < 4; ++r) {
                const int row = m0 + wm + mi * 16 + rb + r;
                out[(size_t)row * DIM + col] = acc[mi][ni][r] + bias;
            }
        }
    }
}

// ---------- launch ----------
extern "C" void kernel_launch(void* const* d_in, const int* in_sizes, int n_in,
                              void* d_out, int out_size, void* d_ws, size_t ws_size,
                              hipStream_t stream) {
    const float* x  = (const float*)d_in[0];
    const float* w2 = (const float*)d_in[1];
    const float* b2 = (const float*)d_in[2];
    const float* wo = (const float*)d_in[3];
    const float* bo = (const float*)d_in[4];
    float* out = (float*)d_out;

    char* ws = (char*)d_ws;
    float*          cws = (float*)ws;                                // 655,360 B
    unsigned short* wob = (unsigned short*)(ws + 655360);            // 2 MB
    unsigned short* ybf = (unsigned short*)(ws + 655360 + 2097152);  // 32 MB
    unsigned short* w2b = (unsigned short*)(ws + 655360 + 2097152 + 33554432); // 192 KB

    cvt_kernel<<<96 + DIM * DIM / 4 / 256, 256, 0, stream>>>(w2, wo, w2b, wob);
    att_coeff_kernel<<<NTOK / ATOK, 256, 0, stream>>>(x, w2b, b2, cws);
    y_kernel<<<NTOK / TT, 256, 0, stream>>>(x, cws, ybf);
    gemm_kernel<<<NTOK / 256 * (DIM / 256), 512, 0, stream>>>(ybf, wob, bo, out);
}

// Round 7
// 87.645 us; speedup vs baseline: 1.4986x; 1.4986x over previous
//
#include <hip/hip_runtime.h>
#include <hip/hip_bf16.h>

#define DIM   1024
#define SEQL  4096
#define NTOK  16384
#define NATT  90
#define NATTP 96

typedef __attribute__((ext_vector_type(8))) short frag_ab;   // 8 x bf16
typedef __attribute__((ext_vector_type(4))) float frag_cd;   // 4 x f32

typedef unsigned int u32;
typedef const __attribute__((address_space(1))) u32* gp_t;
typedef __attribute__((address_space(3))) u32* lp_t;

static __device__ __forceinline__ unsigned short f2bf(float f) {
    unsigned int u = __float_as_uint(f);
    return (unsigned short)((u + 0x7fffu + ((u >> 16) & 1u)) >> 16);  // RNE
}
static __device__ __forceinline__ ushort4 f4tobf(float4 v) {
    ushort4 r; r.x = f2bf(v.x); r.y = f2bf(v.y); r.z = f2bf(v.z); r.w = f2bf(v.w);
    return r;
}

// ---------- cvt: wo -> bf16 (1024 blocks) + w2 -> fragment-packed bf16 (48 blocks) ----
// w2p layout: idx = ((c*6 + f)*64 + lane), 16B per idx.
//   element (c,f,lane) = w2[row = f*16 + (lane&15)][col = c*32 + (lane>>4)*8 .. +7]
//   (rows >= 90 zero). A wave's B-frag load for (c,f) is then 64 lanes x 16B contiguous.
__global__ __launch_bounds__(256) void cvt_kernel(
    const float* __restrict__ w2, const float* __restrict__ wo,
    unsigned short* __restrict__ w2p, unsigned short* __restrict__ wob)
{
    const int bid = blockIdx.x;
    if (bid < 1024) {
        const int i = bid * 256 + threadIdx.x;      // f4 idx over wo
        float4 v = ((const float4*)wo)[i];
        *(ushort4*)(wob + (size_t)i * 4) = f4tobf(v);
    } else {
        const int idx = (bid - 1024) * 256 + threadIdx.x;   // 0..12287
        const int c    = idx / 384;
        const int rem  = idx - c * 384;
        const int f    = rem >> 6;
        const int lane = rem & 63;
        const int row  = f * 16 + (lane & 15);
        const int col  = c * 32 + (lane >> 4) * 8;
        float4 v0 = make_float4(0.f, 0.f, 0.f, 0.f), v1 = v0;
        if (row < NATT) {
            v0 = *(const float4*)(w2 + (size_t)row * DIM + col);
            v1 = *(const float4*)(w2 + (size_t)row * DIM + col + 4);
        }
        unsigned short* dst = w2p + (size_t)idx * 8;
        *(ushort4*)(dst)     = f4tobf(v0);
        *(ushort4*)(dst + 4) = f4tobf(v1);
    }
}

// ---------- stage 1: att = x @ w2^T + b2 -> coeff[9]+absum ----------
// 16 tokens/block, 4 waves K-split (256 cols each). x staged coalesced into
// swizzled LDS bf16; B-frags coalesced from w2p (L2-resident); part-buffer
// reduction (no atomics). part aliases xs after a barrier -> LDS ~39 KB.
#define ATOK 16
#define PSTR 98

__global__ __launch_bounds__(256) void att_coeff_kernel(
    const float* __restrict__ x, const unsigned short* __restrict__ w2p,
    const float* __restrict__ b2, float* __restrict__ cws)
{
    __shared__ __align__(16) char shbuf[ATOK * 1024 * 2];  // 32 KB: xs then part
    __shared__ float summ[ATOK * NATTP];                   // 6 KB
    __shared__ float b2s[NATTP];

    unsigned short* xs   = (unsigned short*)shbuf;         // [16][1024] chunk-swizzled
    float*          part = (float*)shbuf;                  // [4][16][PSTR] (aliases xs)

    const int tid  = threadIdx.x;
    const int wave = tid >> 6, lane = tid & 63;
    const int fr = lane & 15, kq = lane >> 4;
    const int tok0 = blockIdx.x * ATOK;

    if (tid < NATTP) b2s[tid] = (tid < NATT) ? b2[tid] : 0.f;

    // stage x: each wave loads 4 full rows coalesced (1KB/inst), swizzled bf16 store.
    // 16B chunk ch of row r stored at LDS chunk (ch ^ (r&7)).
    #pragma unroll
    for (int t = 0; t < 4; ++t) {
        const int row = t * 4 + wave;
        const float4* xr = (const float4*)(x + (size_t)(tok0 + row) * DIM);
        #pragma unroll
        for (int tt = 0; tt < 4; ++tt) {
            const int c4 = tt * 64 + lane;            // float4 index 0..255
            float4 v = xr[c4];
            const int ch = c4 >> 1, half = c4 & 1;
            *(ushort4*)(&xs[row * 1024 + ((ch ^ (row & 7)) * 8 + half * 4)]) = f4tobf(v);
        }
    }
    __syncthreads();

    // MFMA: wave w owns K chunk-range [w*32, w*32+32) (chunks are 32 cols here: c=0..31)
    frag_cd acc[6] = {};
    #pragma unroll
    for (int kk = 0; kk < 8; ++kk) {
        const int ch = wave * 32 + kk * 4 + kq;       // 16B-chunk idx 0..127
        frag_ab a = *(const frag_ab*)(&xs[fr * 1024 + ((ch ^ (fr & 7)) * 8)]);
        const int c = wave * 8 + kk;                  // 32-col chunk idx 0..31
        #pragma unroll
        for (int f = 0; f < 6; ++f) {
            frag_ab b = *(const frag_ab*)(w2p + ((size_t)((c * 6 + f) * 64) + lane) * 8);
            acc[f] = __builtin_amdgcn_mfma_f32_16x16x32_bf16(a, b, acc[f], 0, 0, 0);
        }
    }
    __syncthreads();   // all waves done reading xs; part may overwrite it

    // partials -> LDS.  D layout: col = lane&15, row = (lane>>4)*4 + r
    const int col = lane & 15, rb = (lane >> 4) * 4;
    #pragma unroll
    for (int f = 0; f < 6; ++f)
        #pragma unroll
        for (int r = 0; r < 4; ++r)
            part[(wave * 16 + rb + r) * PSTR + f * 16 + col] = acc[f][r];
    __syncthreads();

    // sum over the 4 K-slices, add bias
    for (int o = tid; o < ATOK * NATTP; o += 256) {
        const int t = o / NATTP, m = o - (o / NATTP) * NATTP;
        float s = b2s[m];
        #pragma unroll
        for (int w = 0; w < 4; ++w) s += part[(w * 16 + t) * PSTR + m];
        summ[t * NATTP + m] = s;
    }
    __syncthreads();

    // coeff[k] = sum_j sin(att[9k+j]);  absum = sum att[81..89]
    if (tid < 160) {
        const int t = tid / 10, j = tid - (tid / 10) * 10;
        float s = 0.f;
        if (j < 9) {
            #pragma unroll
            for (int jj = 0; jj < 9; ++jj) s += sinf(summ[t * NATTP + j * 9 + jj]);
        } else {
            #pragma unroll
            for (int m = NATT - 9; m < NATT; ++m) s += summ[t * NATTP + m];
        }
        cws[(size_t)(tok0 + t) * 10 + j] = s;
    }
}

// ---------- stage 2: y stencil, rolling register window ----------
#define TT 32

__global__ __launch_bounds__(256) void y_kernel(
    const float* __restrict__ x, const float* __restrict__ cws,
    unsigned short* __restrict__ ybf)
{
    __shared__ float c[TT][10];
    const int tid  = threadIdx.x;
    const int tok0 = blockIdx.x * TT;

    for (int i = tid; i < TT * 10; i += 256)
        c[i / 10][i % 10] = cws[(size_t)tok0 * 10 + i];
    __syncthreads();

    const int b  = tok0 >> 12;
    const int l0 = tok0 & 4095;
    const float4* xv = (const float4*)x + (size_t)b * SEQL * (DIM / 4) + tid;
    const float4 z4 = make_float4(0.f, 0.f, 0.f, 0.f);

    float4 w[9];
    #pragma unroll
    for (int k = 0; k < 8; ++k) {
        const int src = l0 + k - 4;
        w[k] = (src >= 0 && src < SEQL) ? xv[(size_t)src * (DIM / 4)] : z4;
    }

    ushort4* yp = (ushort4*)(ybf + (size_t)tok0 * DIM + tid * 4);

    #pragma unroll
    for (int t = 0; t < TT; ++t) {
        const int src = l0 + t + 4;
        w[8] = (src < SEQL) ? xv[(size_t)src * (DIM / 4)] : z4;

        float4 acc;
        acc.x = acc.y = acc.z = acc.w = c[t][9];
        #pragma unroll
        for (int k = 0; k < 9; ++k) {
            const float ck = c[t][k];
            acc.x += ck * w[k].x; acc.y += ck * w[k].y;
            acc.z += ck * w[k].z; acc.w += ck * w[k].w;
        }
        yp[(size_t)t * (DIM / 4)] = f4tobf(acc);

        #pragma unroll
        for (int k = 0; k < 8; ++k) w[k] = w[k + 1];
    }
}

// ---------- stage 3: out = y @ wo^T + bo ----------
// 256x256 tile, BK=64, 8 waves (2Mx4N), double-buffered LDS, counted vmcnt.
// (round-5 version, measured 43.1 us)
#define GBM 256
#define GBN 256
#define GBK 64

#define STAGE(d, kt)                                                           \
    {                                                                          \
        const int kc_ = (kt) * GBK;                                            \
        _Pragma("unroll")                                                      \
        for (int j_ = 0; j_ < 4; ++j_) {                                       \
            __builtin_amdgcn_global_load_lds(                                  \
                (gp_t)(A + (size_t)(m0 + srow[j_]) * DIM + kc_ + scol[j_]),    \
                (lp_t)(&As[d][(wave * 4 + j_) * 512]), 16, 0, 0);              \
            __builtin_amdgcn_global_load_lds(                                  \
                (gp_t)(Bm + (size_t)(n0 + srow[j_]) * DIM + kc_ + scol[j_]),   \
                (lp_t)(&Bs[d][(wave * 4 + j_) * 512]), 16, 0, 0);              \
        }                                                                      \
    }

__global__ __launch_bounds__(512, 2) void gemm_kernel(
    const unsigned short* __restrict__ A,   // y_bf  [16384][1024]
    const unsigned short* __restrict__ Bm,  // wo_bf [1024][1024] (row = out col)
    const float* __restrict__ bo,
    float* __restrict__ out)
{
    __shared__ unsigned short As[2][GBM * GBK];   // 2 x 32 KB
    __shared__ unsigned short Bs[2][GBN * GBK];   // 2 x 32 KB

    const int tid  = threadIdx.x;
    const int wave = tid >> 6, lane = tid & 63;
    const int fr = lane & 15, kq = lane >> 4;
    const int wm = (wave >> 2) * 128;    // 0 or 128
    const int wn = (wave & 3) * 64;      // 0,64,128,192

    // bijective XCD swizzle: 256 blocks = 8 XCDs x 32; XCD owns 8 contiguous M-panels
    const int bid = blockIdx.x;
    const int lid = (bid & 7) * 32 + (bid >> 3);
    const int m0  = (lid >> 2) * GBM;
    const int n0  = (lid & 3) * GBN;

    int srow[4], scol[4];
    #pragma unroll
    for (int j = 0; j < 4; ++j) {
        int ci = (wave * 4 + j) * 64 + lane;
        int row = ci >> 3;
        srow[j] = row;
        scol[j] = ((ci & 7) ^ (row & 7)) * 8;    // pre-swizzled global source
    }

    frag_cd acc[8][4] = {};

    STAGE(0, 0);
    STAGE(1, 1);

    for (int kt = 0; kt < 15; ++kt) {
        const int d = kt & 1;
        asm volatile("s_waitcnt vmcnt(8)" ::: "memory");   // kt landed; kt+1 in flight
        __builtin_amdgcn_s_barrier();

        frag_ab b0[4], b1[4];
        #pragma unroll
        for (int ni = 0; ni < 4; ++ni) {
            int row = wn + ni * 16 + fr;
            b0[ni] = *(const frag_ab*)(&Bs[d][row * 64 + ((kq       ^ (row & 7)) * 8)]);
            b1[ni] = *(const frag_ab*)(&Bs[d][row * 64 + (((4 + kq) ^ (row & 7)) * 8)]);
        }
        frag_ab alo0[4], alo1[4];
        #pragma unroll
        for (int mi = 0; mi < 4; ++mi) {
            int row = wm + mi * 16 + fr;
            alo0[mi] = *(const frag_ab*)(&As[d][row * 64 + ((kq       ^ (row & 7)) * 8)]);
            alo1[mi] = *(const frag_ab*)(&As[d][row * 64 + (((4 + kq) ^ (row & 7)) * 8)]);
        }
        __builtin_amdgcn_s_setprio(1);
        #pragma unroll
        for (int mi = 0; mi < 4; ++mi)
            #pragma unroll
            for (int ni = 0; ni < 4; ++ni) {
                acc[mi][ni] = __builtin_amdgcn_mfma_f32_16x16x32_bf16(alo0[mi], b0[ni], acc[mi][ni], 0, 0, 0);
                acc[mi][ni] = __builtin_amdgcn_mfma_f32_16x16x32_bf16(alo1[mi], b1[ni], acc[mi][ni], 0, 0, 0);
            }
        __builtin_amdgcn_s_setprio(0);
        frag_ab ahi0[4], ahi1[4];
        #pragma unroll
        for (int mi = 0; mi < 4; ++mi) {
            int row = wm + (mi + 4) * 16 + fr;
            ahi0[mi] = *(const frag_ab*)(&As[d][row * 64 + ((kq       ^ (row & 7)) * 8)]);
            ahi1[mi] = *(const frag_ab*)(&As[d][row * 64 + (((4 + kq) ^ (row & 7)) * 8)]);
        }
        asm volatile("s_waitcnt lgkmcnt(0)" ::: "memory");
        __builtin_amdgcn_s_barrier();
        if (kt < 14) { STAGE(d, kt + 2); }
        __builtin_amdgcn_s_setprio(1);
        #pragma unroll
        for (int mi = 0; mi < 4; ++mi)
            #pragma unroll
            for (int ni = 0; ni < 4; ++ni) {
                acc[mi + 4][ni] = __builtin_amdgcn_mfma_f32_16x16x32_bf16(ahi0[mi], b0[ni], acc[mi + 4][ni], 0, 0, 0);
                acc[mi + 4][ni] = __builtin_amdgcn_mfma_f32_16x16x32_bf16(ahi1[mi], b1[ni], acc[mi + 4][ni], 0, 0, 0);
            }
        __builtin_amdgcn_s_setprio(0);
    }

    {
        asm volatile("s_waitcnt vmcnt(0)" ::: "memory");
        __builtin_amdgcn_s_barrier();
        frag_ab b0[4], b1[4];
        #pragma unroll
        for (int ni = 0; ni < 4; ++ni) {
            int row = wn + ni * 16 + fr;
            b0[ni] = *(const frag_ab*)(&Bs[1][row * 64 + ((kq       ^ (row & 7)) * 8)]);
            b1[ni] = *(const frag_ab*)(&Bs[1][row * 64 + (((4 + kq) ^ (row & 7)) * 8)]);
        }
        #pragma unroll
        for (int h = 0; h < 2; ++h) {
            frag_ab a0[4], a1[4];
            #pragma unroll
            for (int mi = 0; mi < 4; ++mi) {
                int row = wm + (mi + h * 4) * 16 + fr;
                a0[mi] = *(const frag_ab*)(&As[1][row * 64 + ((kq       ^ (row & 7)) * 8)]);
                a1[mi] = *(const frag_ab*)(&As[1][row * 64 + (((4 + kq) ^ (row & 7)) * 8)]);
            }
            __builtin_amdgcn_s_setprio(1);
            #pragma unroll
            for (int mi = 0; mi < 4; ++mi)
                #pragma unroll
                for (int ni = 0; ni < 4; ++ni) {
                    acc[mi + h * 4][ni] = __builtin_amdgcn_mfma_f32_16x16x32_bf16(a0[mi], b0[ni], acc[mi + h * 4][ni], 0, 0, 0);
                    acc[mi + h * 4][ni] = __builtin_amdgcn_mfma_f32_16x16x32_bf16(a1[mi], b1[ni], acc[mi + h * 4][ni], 0, 0, 0);
                }
            __builtin_amdgcn_s_setprio(0);
        }
    }

    // epilogue
    const int colb = lane & 15, rb = (lane >> 4) * 4;
    #pragma unroll
    for (int ni = 0; ni < 4; ++ni) {
        const int col = n0 + wn + ni * 16 + colb;
        const float bias = bo[col];
        #pragma unroll
        for (int mi = 0; mi < 8; ++mi) {
            #pragma unroll
            for (int r = 0; r < 4; ++r) {
                const int row = m0 + wm + mi * 16 + rb + r;
                out[(size_t)row * DIM + col] = acc[mi][ni][r] + bias;
            }
        }
    }
}

// ---------- launch ----------
extern "C" void kernel_launch(void* const* d_in, const int* in_sizes, int n_in,
                              void* d_out, int out_size, void* d_ws, size_t ws_size,
                              hipStream_t stream) {
    const float* x  = (const float*)d_in[0];
    const float* w2 = (const float*)d_in[1];
    const float* b2 = (const float*)d_in[2];
    const float* wo = (const float*)d_in[3];
    const float* bo = (const float*)d_in[4];
    float* out = (float*)d_out;

    char* ws = (char*)d_ws;
    float*          cws = (float*)ws;                                // 655,360 B
    unsigned short* wob = (unsigned short*)(ws + 655360);            // 2 MB
    unsigned short* ybf = (unsigned short*)(ws + 655360 + 2097152);  // 32 MB
    unsigned short* w2p = (unsigned short*)(ws + 655360 + 2097152 + 33554432); // 192 KB

    cvt_kernel<<<1024 + 48, 256, 0, stream>>>(w2, wo, w2p, wob);
    att_coeff_kernel<<<NTOK / ATOK, 256, 0, stream>>>(x, w2p, b2, cws);
    y_kernel<<<NTOK / TT, 256, 0, stream>>>(x, cws, ybf);
    gemm_kernel<<<NTOK / GBM * (DIM / GBN), 512, 0, stream>>>(ybf, wob, bo, out);
}